// Round 5
// baseline (1365.431 us; speedup 1.0000x reference)
//
#include <hip/hip_runtime.h>

// Problem constants (B=8, S=2048, D=512, H=4, HD=128, K=4096)
#define N_TOK 16384          // B*S
#define HEADS 4
#define HD_   128
#define KC    4096
#define XELEMS 8388608       // N_TOK * HEADS * HD_
#define DIFFOFF 8388608
#define IDXOFF  8388609

// Scratch layout inside d_out's quantize region (overwritten by gather at end):
#define EE32_OFF 0           // 16384 floats
#define EE64_OFF 16384       // 16384 doubles = 32768 floats (byte off 65536, 8-aligned)
#define CNT_OFF  49152       // 1 int
#define CAND_OFF 49153       // up to 65536 ints
#define CAND_CAP 65536

#define MARGIN 2.0f          // fp32 main-pass worst realistic error ~0.02 -> 100x slack

// ---------------------------------------------------------------------------
// Kernel 1: ee[h][k] = sum_d embed[h][d][k]^2 in fp64; store fp32 + fp64.
// ---------------------------------------------------------------------------
__global__ __launch_bounds__(256) void vq_ee_kernel(const float* __restrict__ e,
                                                    float* __restrict__ ee32,
                                                    double* __restrict__ ee64) {
  int h = blockIdx.y;
  int k = blockIdx.x * 256 + threadIdx.x;
  const float* eh = e + (size_t)h * HD_ * KC;
  double s = 0.0;
#pragma unroll 8
  for (int d = 0; d < HD_; ++d) {
    double v = (double)eh[(size_t)d * KC + k];
    s = fma(v, v, s);
  }
  ee32[h * KC + k] = (float)s;
  ee64[h * KC + k] = s;
}

// ---------------------------------------------------------------------------
// Kernel 2: fp32 distance + argmin with second-best margin test.
// Rows whose (second - best) < MARGIN are flagged for fp64 rescue.
// ---------------------------------------------------------------------------
__global__ __launch_bounds__(256, 2) void vq_argmin_kernel(
    const float* __restrict__ x, const float* __restrict__ e,
    const float* __restrict__ ee, float* __restrict__ idx_out,
    int* __restrict__ cnt, int* __restrict__ cand) {
  __shared__ float xs[HD_][64];
  __shared__ float es[HD_][64];
  __shared__ float xx[64];
  __shared__ float redV[64][16];
  __shared__ float redV2[64][16];
  __shared__ int   redI[64][16];

  const int t  = threadIdx.x;
  const int h  = blockIdx.y;
  const int n0 = blockIdx.x * 64;
  const int tc = t & 15;   // code group (4 codes)
  const int tr = t >> 4;   // row group (4 rows)
  const float* eh = e + (size_t)h * HD_ * KC;

  // ---- stage x tile transposed: xs[d][r] ----
  {
    const int c = t & 31, r0 = t >> 5;
#pragma unroll
    for (int i = 0; i < 8; ++i) {
      int r = i * 8 + r0;
      float4 v = *reinterpret_cast<const float4*>(
          x + ((size_t)(n0 + r) * HEADS + h) * HD_ + c * 4);
      xs[c * 4 + 0][r] = v.x;
      xs[c * 4 + 1][r] = v.y;
      xs[c * 4 + 2][r] = v.z;
      xs[c * 4 + 3][r] = v.w;
    }
  }
  __syncthreads();

  // ---- per-row ||x||^2 (row-uniform: cannot affect argmin ordering) ----
  if (t < 64) {
    float s = 0.f;
    for (int d = 0; d < HD_; ++d) { float v = xs[d][t]; s = fmaf(v, v, s); }
    xx[t] = s;
  }
  __syncthreads();

  float xxr[4];
#pragma unroll
  for (int i = 0; i < 4; ++i) xxr[i] = xx[tr * 4 + i];

  float b1[4], b2[4];
  int   i1[4];
#pragma unroll
  for (int i = 0; i < 4; ++i) { b1[i] = __builtin_inff(); b2[i] = __builtin_inff(); i1[i] = 0; }

  for (int k0 = 0; k0 < KC; k0 += 64) {
    __syncthreads();  // protect es reuse across iterations
    {                 // stage e tile: es[d][c] for codes k0..k0+63
      const int c = t & 15, d0 = t >> 4;
#pragma unroll
      for (int i = 0; i < 8; ++i) {
        int d = i * 16 + d0;
        *reinterpret_cast<float4*>(&es[d][c * 4]) =
            *reinterpret_cast<const float4*>(eh + (size_t)d * KC + k0 + c * 4);
      }
    }
    __syncthreads();

    float acc[4][4];
#pragma unroll
    for (int i = 0; i < 4; ++i)
#pragma unroll
      for (int j = 0; j < 4; ++j) acc[i][j] = 0.f;

#pragma unroll 4
    for (int d = 0; d < HD_; ++d) {
      float4 xv = *reinterpret_cast<const float4*>(&xs[d][tr * 4]);
      float4 ev = *reinterpret_cast<const float4*>(&es[d][tc * 4]);
      float xa[4] = {xv.x, xv.y, xv.z, xv.w};
      float ea[4] = {ev.x, ev.y, ev.z, ev.w};
#pragma unroll
      for (int i = 0; i < 4; ++i)
#pragma unroll
        for (int j = 0; j < 4; ++j) acc[i][j] = fmaf(xa[i], ea[j], acc[i][j]);
    }

    float4 eev = *reinterpret_cast<const float4*>(ee + h * KC + k0 + tc * 4);
    float ea[4] = {eev.x, eev.y, eev.z, eev.w};
    const int code0 = k0 + tc * 4;
#pragma unroll
    for (int j = 0; j < 4; ++j) {
#pragma unroll
      for (int i = 0; i < 4; ++i) {
        float val = (xxr[i] - 2.0f * acc[i][j]) + ea[j];
        if (val < b1[i]) { b2[i] = b1[i]; b1[i] = val; i1[i] = code0 + j; }
        else if (val < b2[i]) { b2[i] = val; }
      }
    }
  }

  // ---- cross-thread (tc) reduction per row: best + second-best ----
  __syncthreads();
#pragma unroll
  for (int i = 0; i < 4; ++i) {
    redV [tr * 4 + i][tc] = b1[i];
    redV2[tr * 4 + i][tc] = b2[i];
    redI [tr * 4 + i][tc] = i1[i];
  }
  __syncthreads();
  if (t < 64) {
    float bv1 = redV[t][0], bv2 = redV2[t][0];
    int   bi1 = redI[t][0];
#pragma unroll
    for (int c = 1; c < 16; ++c) {
      float v1 = redV[t][c], v2 = redV2[t][c];
      int  ci = redI[t][c];
      if (v1 < bv1 || (v1 == bv1 && ci < bi1)) {
        bv2 = fminf(bv1, v2);
        bv1 = v1; bi1 = ci;
      } else {
        bv2 = fminf(bv2, v1);
      }
    }
    idx_out[(size_t)(n0 + t) * HEADS + h] = (float)bi1;
    if (bv2 - bv1 < MARGIN) {  // near-tie: needs fp64 rescue
      int slot = atomicAdd(cnt, 1);
      if (slot < CAND_CAP) cand[slot] = (n0 + t) * HEADS + h;
    }
  }
}

// ---------------------------------------------------------------------------
// Kernel 2b: fp64 exact rescue for flagged rows (grid-stride over candidates)
// ---------------------------------------------------------------------------
__global__ __launch_bounds__(256) void vq_rescue_kernel(
    const float* __restrict__ x, const float* __restrict__ e,
    const double* __restrict__ ee64, const int* __restrict__ cand,
    const int* __restrict__ cntp, float* __restrict__ idx_out) {
  __shared__ float  xrow[HD_];
  __shared__ double rv[256];
  __shared__ int    ri[256];
  int count = *cntp;
  if (count > CAND_CAP) count = CAND_CAP;
  for (int c = blockIdx.x; c < count; c += gridDim.x) {
    int nh = cand[c];
    int n = nh >> 2, h = nh & 3;
    if (threadIdx.x < HD_)
      xrow[threadIdx.x] = x[((size_t)n * HEADS + h) * HD_ + threadIdx.x];
    __syncthreads();
    const float* eh = e + (size_t)h * HD_ * KC;
    double bv = __builtin_inf();
    int bi = 0;
    for (int k = threadIdx.x; k < KC; k += 256) {
      double dot = 0.0;
#pragma unroll 8
      for (int d = 0; d < HD_; ++d)
        dot = fma((double)xrow[d], (double)eh[(size_t)d * KC + k], dot);
      double v = ee64[h * KC + k] - 2.0 * dot;  // ||x||^2 row-uniform: dropped
      if (v < bv || (v == bv && k < bi)) { bv = v; bi = k; }
    }
    rv[threadIdx.x] = bv; ri[threadIdx.x] = bi;
    __syncthreads();
    for (int s2 = 128; s2 > 0; s2 >>= 1) {
      if (threadIdx.x < s2) {
        double v2 = rv[threadIdx.x + s2]; int idx2 = ri[threadIdx.x + s2];
        if (v2 < rv[threadIdx.x] ||
            (v2 == rv[threadIdx.x] && idx2 < ri[threadIdx.x])) {
          rv[threadIdx.x] = v2; ri[threadIdx.x] = idx2;
        }
      }
      __syncthreads();
    }
    if (threadIdx.x == 0) idx_out[(size_t)n * HEADS + h] = (float)ri[0];
    __syncthreads();
  }
}

// ---------------------------------------------------------------------------
// Kernel 3: gather quantize output + L1 mean (atomic per block)
// ---------------------------------------------------------------------------
__global__ __launch_bounds__(256) void vq_gather_kernel(
    const float* __restrict__ x, const float* __restrict__ e,
    const float* __restrict__ idxf, float* __restrict__ out,
    float* __restrict__ diffp) {
  const size_t stride = (size_t)gridDim.x * 256;
  float local = 0.f;
  for (size_t f = (size_t)blockIdx.x * 256 + threadIdx.x; f < XELEMS; f += stride) {
    int n  = (int)(f >> 9);
    int rh = (int)(f & 511);
    int h  = rh >> 7;
    int d  = rh & 127;
    int k  = (int)idxf[n * HEADS + h];
    float q  = e[(size_t)(h * HD_ + d) * KC + k];
    float xv = x[f];
    out[f] = q;
    local += fabsf(xv - q);
  }
  for (int o = 32; o > 0; o >>= 1) local += __shfl_down(local, o, 64);
  __shared__ float ws[4];
  int lane = threadIdx.x & 63, w = threadIdx.x >> 6;
  if (lane == 0) ws[w] = local;
  __syncthreads();
  if (threadIdx.x == 0) {
    float s = (ws[0] + ws[1] + ws[2] + ws[3]) * (1.0f / 8388608.0f);
    atomicAdd(diffp, s);
  }
}

// ---------------------------------------------------------------------------
extern "C" void kernel_launch(void* const* d_in, const int* in_sizes, int n_in,
                              void* d_out, int out_size, void* d_ws, size_t ws_size,
                              hipStream_t stream) {
  const float* x = (const float*)d_in[0];
  const float* e = (const float*)d_in[1];
  float* out   = (float*)d_out;
  float*  ee32 = out + EE32_OFF;            // scratch in quantize region
  double* ee64 = (double*)(out + EE64_OFF); // byte offset 65536, 8-aligned
  int*    cnt  = (int*)(out + CNT_OFF);
  int*    cand = (int*)(out + CAND_OFF);
  float* diffp = out + DIFFOFF;
  float* idxp  = out + IDXOFF;

  hipMemsetAsync(diffp, 0, sizeof(float), stream);
  hipMemsetAsync(cnt, 0, sizeof(int), stream);
  vq_ee_kernel<<<dim3(KC / 256, HEADS), 256, 0, stream>>>(e, ee32, ee64);
  vq_argmin_kernel<<<dim3(N_TOK / 64, HEADS), 256, 0, stream>>>(x, e, ee32, idxp, cnt, cand);
  vq_rescue_kernel<<<128, 256, 0, stream>>>(x, e, ee64, cand, cnt, idxp);
  vq_gather_kernel<<<2048, 256, 0, stream>>>(x, e, idxp, out, diffp);
}